// Round 4
// baseline (431.532 us; speedup 1.0000x reference)
//
#include <hip/hip_runtime.h>

// PortfolioGenerator: B=16384 rows of S=2048 fp32 scores.
// long = scatter(softmax(top256)), short = scatter(softmax(1-bottom256))
//      = softmax(-bottom256) by shift invariance; plus clipped short_ratio.
//
// R4: single fused kernel, one wave per row, zero __syncthreads.
//  - per-wave LDS 256-bin value histogram (bin width 1/64 over [-2,2)) to
//    locate the rank-256 boundary bin for both directions,
//  - exact cutoff inside the boundary bin via repeated wave-max over packed
//    u64 keys (f2key(v)<<32 | ~idx) — register/shuffle only, no LDS gather,
//    no dynamic-indexed arrays (would spill to scratch). Extract from the
//    cheaper end of the bin: min(need, cnt-need+1) iterations (~2 avg).
//  - tie order matches jax top_k: value desc (asc for losers), index asc.

#define NT   256
#define WPB  4      // waves (=rows) per block
#define SDIM 2048
#define KSEL 256u
#define EPL  32     // elements per lane (2048 / 64)

__device__ __forceinline__ unsigned f2key(float f) {
    unsigned u = __float_as_uint(f);
    return (u & 0x80000000u) ? ~u : (u | 0x80000000u);  // monotone float->uint
}
__device__ __forceinline__ float key2f(unsigned k) {
    unsigned u = (k & 0x80000000u) ? (k & 0x7FFFFFFFu) : ~k;
    return __uint_as_float(u);
}
__device__ __forceinline__ int binOf(float x) {
    int b = (int)__builtin_fmaf(x, 64.f, 128.f);  // trunc: monotone after clamp
    return min(max(b, 0), 255);
}

// Exact rank-`need` cutoff among this wave's elements whose mask bit is set.
// Ordering: descending by key kv(v) = (losers ? ~f2key : f2key), ties by
// index asc (encoded as |~idx). Returns packed cutoff key (kv<<32 | ~idx).
__device__ __forceinline__ unsigned long long extract_cut(
    const float v[EPL], unsigned mask, unsigned need, unsigned cnt, int lane,
    bool losers) {
    const unsigned nTop = need, nBot = cnt - need + 1;
    const bool     bot  = nBot < nTop;
    const unsigned nIt  = bot ? nBot : nTop;
    const unsigned long long flip = bot ? ~0ull : 0ull;  // order reversal
    unsigned long long cut = 0;
    for (unsigned it = 0; it < nIt; ++it) {
        unsigned long long best = 0;
        int                bj   = -1;
#pragma unroll
        for (int j = 0; j < EPL; ++j) {
            if (mask & (1u << j)) {
                unsigned kv = f2key(v[j]);
                if (losers) kv = ~kv;
                const unsigned idx =
                    (unsigned)((j >> 2) * 256 + lane * 4 + (j & 3));
                const unsigned long long k =
                    (((unsigned long long)kv << 32) | (unsigned)~idx) ^ flip;
                if (k > best) { best = k; bj = j; }
            }
        }
        unsigned long long w = best;
#pragma unroll
        for (int off = 32; off; off >>= 1) {
            const unsigned long long o =
                (unsigned long long)__shfl_xor((long long)w, off);
            if (o > w) w = o;
        }
        if (best == w && bj >= 0) mask &= ~(1u << bj);  // unique key -> 1 owner
        cut = w;
    }
    return cut ^ flip;
}

__global__ void __launch_bounds__(NT) portfolio_kernel(
    const float* __restrict__ scores, const float* __restrict__ short_ratio,
    float* __restrict__ out_long, float* __restrict__ out_short,
    float* __restrict__ out_sr) {
    __shared__ unsigned s_hist[WPB][256];

    const int    lane = threadIdx.x & 63;
    const int    wv   = threadIdx.x >> 6;
    const int    row  = blockIdx.x * WPB + wv;
    const size_t base = (size_t)row * SDIM;

    // ---- load 32 elems/lane; elem (i,c) has idx = i*256 + lane*4 + c ------
    const float4* rp = (const float4*)(scores + base);
    float v[EPL];
#pragma unroll
    for (int i = 0; i < 8; ++i) {
        const float4 a = rp[i * 64 + lane];
        v[4 * i + 0] = a.x;
        v[4 * i + 1] = a.y;
        v[4 * i + 2] = a.z;
        v[4 * i + 3] = a.w;
    }

    // ---- clear hist quad, then bins (packed) + atomics + local max/min ----
    unsigned* hist = s_hist[wv];
    *((uint4*)&hist[lane * 4]) = make_uint4(0u, 0u, 0u, 0u);
    float    vmax = v[0], vmin = v[0];
    unsigned pb[8];  // 4 x 8-bit bin ids per word
#pragma unroll
    for (int i = 0; i < 8; ++i) {
        unsigned p = 0;
#pragma unroll
        for (int c = 0; c < 4; ++c) {
            const int j = 4 * i + c;
            vmax = fmaxf(vmax, v[j]);
            vmin = fminf(vmin, v[j]);
            const int b = binOf(v[j]);
            p |= (unsigned)b << (8 * c);
            atomicAdd(&hist[b], 1u);
        }
        pb[i] = p;
    }
#pragma unroll
    for (int off = 32; off; off >>= 1) {
        vmax = fmaxf(vmax, __shfl_xor(vmax, off));
        vmin = fminf(vmin, __shfl_xor(vmin, off));
    }

    // ---- prefix scan over 256 bins (lane owns 4); find boundary bins ------
    const uint4 h   = *((const uint4*)&hist[lane * 4]);
    unsigned    p0  = h.x, p1 = p0 + h.y, p2 = p1 + h.z, p3 = p2 + h.w;
    unsigned    pre = p3;
#pragma unroll
    for (int off = 1; off < 64; off <<= 1) {
        const unsigned x = __shfl_up(pre, off);
        if (lane >= off) pre += x;
    }
    const unsigned before = pre - p3;  // elems in bins < 4*lane
    const unsigned L[5]   = {before, before + p0, before + p1, before + p2,
                             before + p3};
    const unsigned T = (unsigned)SDIM;

    int      bwLoc = -1, blLoc = -1;
    unsigned needwLoc = 0, CwLoc = 0, needlLoc = 0, ClLoc = 0;
#pragma unroll
    for (int c = 0; c < 4; ++c) {
        const unsigned cnt_b = (c == 0) ? h.x : (c == 1) ? h.y
                                        : (c == 2) ? h.z : h.w;
        const unsigned tc = T - L[c], tcn = T - L[c + 1];
        if (tc >= KSEL && tcn < KSEL) {          // winner bin (from the top)
            bwLoc    = lane * 4 + c;
            needwLoc = KSEL - tcn;
            CwLoc    = cnt_b;
        }
        if (L[c + 1] >= KSEL && L[c] < KSEL) {   // loser bin (from the bottom)
            blLoc    = lane * 4 + c;
            needlLoc = KSEL - L[c];
            ClLoc    = cnt_b;
        }
    }
    const unsigned long long mWb = __ballot(bwLoc >= 0);
    const unsigned long long mLb = __ballot(blLoc >= 0);
    const int swl = __ffsll(mWb) - 1, sll = __ffsll(mLb) - 1;
    const int      bw    = __shfl(bwLoc, swl);
    const unsigned needw = (unsigned)__shfl((int)needwLoc, swl);
    const unsigned Cw    = (unsigned)__shfl((int)CwLoc, swl);
    const int      bl    = __shfl(blLoc, sll);
    const unsigned needl = (unsigned)__shfl((int)needlLoc, sll);
    const unsigned Cl    = (unsigned)__shfl((int)ClLoc, sll);

    // ---- candidate masks for both boundary bins ---------------------------
    unsigned maskW = 0, maskL = 0;
#pragma unroll
    for (int i = 0; i < 8; ++i) {
#pragma unroll
        for (int c = 0; c < 4; ++c) {
            const int b = (int)((pb[i] >> (8 * c)) & 255u);
            maskW |= (unsigned)(b == bw) << (4 * i + c);
            maskL |= (unsigned)(b == bl) << (4 * i + c);
        }
    }

    // ---- exact cutoffs (register/shuffle only) ----------------------------
    const unsigned long long kW = extract_cut(v, maskW, needw, Cw, lane, false);
    const unsigned long long kL = extract_cut(v, maskL, needl, Cl, lane, true);
    const float    cutVw = key2f((unsigned)(kW >> 32));
    const unsigned cutIw = ~(unsigned)kW;
    const float    cutVl = key2f(~(unsigned)(kL >> 32));
    const unsigned cutIl = ~(unsigned)kL;

    // ---- softmax denominators (one arg-selected exp per element) ----------
    float sumW = 0.f, sumL = 0.f;
#pragma unroll
    for (int j = 0; j < EPL; ++j) {
        const unsigned idx  = (unsigned)((j >> 2) * 256 + lane * 4 + (j & 3));
        const bool     selw = (v[j] > cutVw) || (v[j] == cutVw && idx <= cutIw);
        const bool     sell = (v[j] < cutVl) || (v[j] == cutVl && idx <= cutIl);
        const float    e    = __expf(selw ? (v[j] - vmax) : (vmin - v[j]));
        if (selw) sumW += e;
        if (sell) sumL += e;
    }
#pragma unroll
    for (int off = 32; off; off >>= 1) {
        sumW += __shfl_xor(sumW, off);
        sumL += __shfl_xor(sumL, off);
    }
    const float izw = 1.f / sumW, izl = 1.f / sumL;

    // ---- dense writes straight from registers (coalesced float4) ----------
    float4* lp = (float4*)(out_long + base);
    float4* sp = (float4*)(out_short + base);
#pragma unroll
    for (int i = 0; i < 8; ++i) {
        float lw[4], sw[4];
#pragma unroll
        for (int c = 0; c < 4; ++c) {
            const int      j    = 4 * i + c;
            const unsigned idx  = (unsigned)(i * 256 + lane * 4 + c);
            const bool     selw = (v[j] > cutVw) || (v[j] == cutVw && idx <= cutIw);
            const bool     sell = (v[j] < cutVl) || (v[j] == cutVl && idx <= cutIl);
            const float    e    = __expf(selw ? (v[j] - vmax) : (vmin - v[j]));
            lw[c] = selw ? e * izw : 0.f;
            sw[c] = sell ? e * izl : 0.f;
        }
        lp[i * 64 + lane] = make_float4(lw[0], lw[1], lw[2], lw[3]);
        sp[i * 64 + lane] = make_float4(sw[0], sw[1], sw[2], sw[3]);
    }
    if (lane == 0) out_sr[row] = fminf(fmaxf(short_ratio[row], 0.f), 1.f);
}

extern "C" void kernel_launch(void* const* d_in, const int* in_sizes, int n_in,
                              void* d_out, int out_size, void* d_ws,
                              size_t ws_size, hipStream_t stream) {
    const float* scores = (const float*)d_in[0];
    const float* sr     = (const float*)d_in[1];
    const int    B      = in_sizes[1];  // 16384
    float* out       = (float*)d_out;
    float* out_long  = out;
    float* out_short = out + (size_t)B * SDIM;
    float* out_sr    = out + 2 * (size_t)B * SDIM;
    portfolio_kernel<<<B / WPB, NT, 0, stream>>>(scores, sr, out_long,
                                                 out_short, out_sr);
}

// Round 5
// 374.262 us; speedup vs baseline: 1.1530x; 1.1530x over previous
//
#include <hip/hip_runtime.h>

// PortfolioGenerator: B=16384 rows of S=2048 fp32 scores.
// long = scatter(softmax(top256)), short = scatter(softmax(1-bottom256))
//      = softmax(-bottom256) by shift invariance; plus clipped short_ratio.
//
// R5: fused, one wave/row, zero __syncthreads.
//  - per-wave LDS 256-bin value histogram locates the rank-256 boundary bin
//    for both directions (bins of width 1/64 over [-2,2), clamped edges).
//  - exact in-bin selection via incremental per-lane-best extraction:
//    one 32-elem scan per direction, then per iteration only a 32-bit
//    wave-max (+ rare idx tie-break); winner lane promotes its next-best
//    (execz-skipped when it has no more candidates). Extracts from the
//    cheaper end: min(need, cnt-need+1) iterations (~2 avg).
//  - extraction returns the in-bin SELECTION BITMASK -> final per-element
//    predicate is a bit test; exp computed once (stored over v[]).
//  - tie order matches jax top_k: value desc (asc for losers), index asc.

#define NT   256
#define WPB  4      // waves (=rows) per block
#define SDIM 2048
#define KSEL 256u
#define EPL  32     // elements per lane (2048 / 64)

typedef float vf4 __attribute__((ext_vector_type(4)));

__device__ __forceinline__ unsigned f2key(float f) {
    const unsigned u = __float_as_uint(f);
    return (u & 0x80000000u) ? ~u : (u | 0x80000000u);  // monotone float->uint
}
__device__ __forceinline__ int binOf(float x) {
    const int b = (int)__builtin_fmaf(x, 64.f, 128.f);
    return min(max(b, 0), 255);
}
__device__ __forceinline__ unsigned wredmax(unsigned x) {
#pragma unroll
    for (int off = 32; off; off >>= 1) {
        const unsigned o = (unsigned)__shfl_xor((int)x, off);
        if (o > x) x = o;
    }
    return x;
}
__device__ __forceinline__ unsigned wredmin(unsigned x) {
#pragma unroll
    for (int off = 32; off; off >>= 1) {
        const unsigned o = (unsigned)__shfl_xor((int)x, off);
        if (o < x) x = o;
    }
    return x;
}

struct Best { unsigned kv, ix; int j; };

// Per-lane best candidate among `rem` bits; order: kv desc, ix asc
// (kv = f2key(v)^kxor, ix = idx^ixor).
__device__ __forceinline__ Best scanBest(const float* v, unsigned rem,
                                         unsigned kxor, unsigned ixor,
                                         int lane) {
    Best b;
    b.kv = 0u; b.ix = 0xFFFFFFFFu; b.j = -1;
#pragma unroll
    for (int j = 0; j < EPL; ++j) {
        if (rem & (1u << j)) {
            const unsigned kv = f2key(v[j]) ^ kxor;
            const unsigned ix =
                ((unsigned)((j >> 2) * 256 + (j & 3)) + (unsigned)lane * 4u) ^
                ixor;
            const bool better =
                (b.j < 0) || (kv > b.kv) || (kv == b.kv && ix < b.ix);
            if (better) { b.kv = kv; b.ix = ix; b.j = j; }
        }
    }
    return b;
}

// Per-lane bitmask of `cand` elements in the selected top-`need` of the bin.
// Direction order: desc by (f2key^dirXor), ties idx asc (jax top_k stable).
__device__ __forceinline__ unsigned extract_sel(const float* v, unsigned cand,
                                                unsigned need, unsigned cnt,
                                                unsigned dirXor, int lane) {
    const unsigned nTop = need, nBot = cnt - need + 1u;
    const bool     bot  = nBot < nTop;
    const unsigned nIt  = bot ? nBot : nTop;
    const unsigned rev  = bot ? 0xFFFFFFFFu : 0u;  // reversed order from far end
    const unsigned kxor = dirXor ^ rev;
    const unsigned ixor = rev;

    unsigned rem = cand;
    Best     b   = scanBest(v, rem, kxor, ixor, lane);
    if (b.j >= 0) rem &= ~(1u << b.j);

    unsigned removed = 0u, lastBit = 0u;
    for (unsigned it = 0; it < nIt; ++it) {
        const unsigned kvv = (b.j >= 0) ? b.kv : 0u;
        const unsigned wkv = wredmax(kvv);
        const bool inrun   = (b.j >= 0) && (b.kv == wkv);
        bool       mine;
        const unsigned long long bal = __ballot(inrun);
        if (__popcll(bal) > 1) {  // duplicate values across lanes (rare)
            const unsigned ixc = inrun ? b.ix : 0xFFFFFFFFu;
            const unsigned wix = wredmin(ixc);
            mine = inrun && (b.ix == wix);
        } else {
            mine = inrun;
        }
        if (mine) {
            const unsigned bit = 1u << b.j;
            removed |= bit;
            if (it == nIt - 1u) lastBit = bit;
            b.j = -1;
        }
        if (mine && rem) {  // promote next-best (<=1 lane; usually skipped)
            b = scanBest(v, rem, kxor, ixor, lane);
            rem &= ~(1u << b.j);
        }
    }
    // top path: removed = selected. bot path: selected = never-removed + cutoff.
    return bot ? ((cand & ~removed) | lastBit) : removed;
}

__global__ void __launch_bounds__(NT) portfolio_kernel(
    const float* __restrict__ scores, const float* __restrict__ short_ratio,
    float* __restrict__ out_long, float* __restrict__ out_short,
    float* __restrict__ out_sr) {
    __shared__ unsigned s_hist[WPB][256];

    const int    lane = threadIdx.x & 63;
    const int    wv   = threadIdx.x >> 6;
    const int    row  = blockIdx.x * WPB + wv;
    const size_t base = (size_t)row * SDIM;

    // ---- load 32 elems/lane; elem (i,c) has idx = i*256 + lane*4 + c ------
    const float4* rp = (const float4*)(scores + base);
    float v[EPL];
#pragma unroll
    for (int i = 0; i < 8; ++i) {
        const float4 a = rp[i * 64 + lane];
        v[4 * i + 0] = a.x;
        v[4 * i + 1] = a.y;
        v[4 * i + 2] = a.z;
        v[4 * i + 3] = a.w;
    }

    // ---- clear hist quad; bins (packed) + atomics + local max/min ---------
    unsigned* hist = s_hist[wv];
    *((uint4*)&hist[lane * 4]) = make_uint4(0u, 0u, 0u, 0u);
    float    vmax = v[0], vmin = v[0];
    unsigned pb[8];
#pragma unroll
    for (int i = 0; i < 8; ++i) {
        unsigned p = 0;
#pragma unroll
        for (int c = 0; c < 4; ++c) {
            const int j = 4 * i + c;
            vmax = fmaxf(vmax, v[j]);
            vmin = fminf(vmin, v[j]);
            const int b = binOf(v[j]);
            p |= (unsigned)b << (8 * c);
            atomicAdd(&hist[b], 1u);
        }
        pb[i] = p;
    }
#pragma unroll
    for (int off = 32; off; off >>= 1) {
        vmax = fmaxf(vmax, __shfl_xor(vmax, off));
        vmin = fminf(vmin, __shfl_xor(vmin, off));
    }

    // ---- prefix scan over 256 bins (lane owns 4); find boundary bins ------
    const uint4 h   = *((const uint4*)&hist[lane * 4]);
    unsigned    p0  = h.x, p1 = p0 + h.y, p2 = p1 + h.z, p3 = p2 + h.w;
    unsigned    pre = p3;
#pragma unroll
    for (int off = 1; off < 64; off <<= 1) {
        const unsigned x = __shfl_up(pre, off);
        if (lane >= off) pre += x;
    }
    const unsigned before = pre - p3;  // elems in bins < 4*lane
    const unsigned L[5]   = {before, before + p0, before + p1, before + p2,
                             before + p3};
    const unsigned T = (unsigned)SDIM;

    int      bwLoc = -1, blLoc = -1;
    unsigned needwLoc = 0, CwLoc = 0, needlLoc = 0, ClLoc = 0;
#pragma unroll
    for (int c = 0; c < 4; ++c) {
        const unsigned cb = (c == 0) ? h.x : (c == 1) ? h.y
                                      : (c == 2) ? h.z : h.w;
        const unsigned tc = T - L[c], tcn = T - L[c + 1];
        if (tc >= KSEL && tcn < KSEL) {          // winner bin (from the top)
            bwLoc    = lane * 4 + c;
            needwLoc = KSEL - tcn;
            CwLoc    = cb;
        }
        if (L[c + 1] >= KSEL && L[c] < KSEL) {   // loser bin (from the bottom)
            blLoc    = lane * 4 + c;
            needlLoc = KSEL - L[c];
            ClLoc    = cb;
        }
    }
    const unsigned long long mWb = __ballot(bwLoc >= 0);
    const unsigned long long mLb = __ballot(blLoc >= 0);
    const int swl = __ffsll(mWb) - 1, sll = __ffsll(mLb) - 1;
    const int      bw    = __shfl(bwLoc, swl);
    const unsigned needw = (unsigned)__shfl((int)needwLoc, swl);
    const unsigned Cw    = (unsigned)__shfl((int)CwLoc, swl);
    const int      bl    = __shfl(blLoc, sll);
    const unsigned needl = (unsigned)__shfl((int)needlLoc, sll);
    const unsigned Cl    = (unsigned)__shfl((int)ClLoc, sll);

    // ---- candidate masks + guaranteed-selected bits -----------------------
    unsigned maskW = 0, maskL = 0, gtW = 0, ltL = 0;
#pragma unroll
    for (int i = 0; i < 8; ++i) {
#pragma unroll
        for (int c = 0; c < 4; ++c) {
            const int b = (int)((pb[i] >> (8 * c)) & 255u);
            const int j = 4 * i + c;
            maskW |= (unsigned)(b == bw) << j;
            gtW   |= (unsigned)(b >  bw) << j;
            maskL |= (unsigned)(b == bl) << j;
            ltL   |= (unsigned)(b <  bl) << j;
        }
    }

    // ---- exact in-bin selection masks (register/shuffle only) -------------
    const unsigned selW = gtW | extract_sel(v, maskW, needw, Cw, 0u, lane);
    const unsigned selL = ltL | extract_sel(v, maskL, needl, Cl, 0xFFFFFFFFu, lane);

    // ---- exp once per element (stored over v) + softmax denominators ------
    float sumW = 0.f, sumL = 0.f;
#pragma unroll
    for (int j = 0; j < EPL; ++j) {
        const bool  sw_ = (selW >> j) & 1u;
        const bool  sl_ = (selL >> j) & 1u;
        const float e   = __expf(sw_ ? (v[j] - vmax) : (vmin - v[j]));
        v[j] = e;
        if (sw_) sumW += e;
        if (sl_) sumL += e;
    }
#pragma unroll
    for (int off = 32; off; off >>= 1) {
        sumW += __shfl_xor(sumW, off);
        sumL += __shfl_xor(sumL, off);
    }
    const float izw = 1.f / sumW, izl = 1.f / sumL;

    // ---- dense streaming writes (nontemporal; never re-read) --------------
    vf4* lp = (vf4*)(out_long + base);
    vf4* sp = (vf4*)(out_short + base);
#pragma unroll
    for (int i = 0; i < 8; ++i) {
        vf4 lw, sw;
#pragma unroll
        for (int c = 0; c < 4; ++c) {
            const int j = 4 * i + c;
            lw[c] = ((selW >> j) & 1u) ? v[j] * izw : 0.f;
            sw[c] = ((selL >> j) & 1u) ? v[j] * izl : 0.f;
        }
        __builtin_nontemporal_store(lw, &lp[i * 64 + lane]);
        __builtin_nontemporal_store(sw, &sp[i * 64 + lane]);
    }
    if (lane == 0) out_sr[row] = fminf(fmaxf(short_ratio[row], 0.f), 1.f);
}

extern "C" void kernel_launch(void* const* d_in, const int* in_sizes, int n_in,
                              void* d_out, int out_size, void* d_ws,
                              size_t ws_size, hipStream_t stream) {
    const float* scores = (const float*)d_in[0];
    const float* sr     = (const float*)d_in[1];
    const int    B      = in_sizes[1];  // 16384
    float* out       = (float*)d_out;
    float* out_long  = out;
    float* out_short = out + (size_t)B * SDIM;
    float* out_sr    = out + 2 * (size_t)B * SDIM;
    portfolio_kernel<<<B / WPB, NT, 0, stream>>>(scores, sr, out_long,
                                                 out_short, out_sr);
}